// Round 5
// baseline (7882.951 us; speedup 1.0000x reference)
//
#include <hip/hip_runtime.h>

#define BB 256
#define TT 512
#define DD 200

// ---------- helpers ----------
__device__ __forceinline__ float sigm(float x) { return 1.0f / (1.0f + __expf(-x)); }
__device__ __forceinline__ float tanh_(float x) { return 1.0f - 2.0f / (__expf(2.0f * x) + 1.0f); }

// ---------- TwoStageFusion, one token per block, pre-shifted output ----------
// Row m (= b*R + tl, token t = tbase+tl) of gout holds gamma(b, t-1); zeros if t==0.
__global__ __launch_bounds__(128) void k_gamma(
    const float* __restrict__ ac, const float* __restrict__ pc,
    const float* __restrict__ rd,
    const float* __restrict__ w_amp, const float* __restrict__ b_amp,
    const float* __restrict__ w_ph,  const float* __restrict__ b_ph,
    const float* __restrict__ w_g,   const float* __restrict__ b_g,
    const float* __restrict__ w_r1,  const float* __restrict__ b_r1,
    const float* __restrict__ w_r2,  const float* __restrict__ b_r2,
    const float* __restrict__ w_q,   const float* __restrict__ b_q,
    const float* __restrict__ w_k,   const float* __restrict__ b_k,
    const float* __restrict__ w_v,   const float* __restrict__ b_v,
    const float* __restrict__ w_o,   const float* __restrict__ b_o,
    float* __restrict__ gout, int R, int lg, int tbase)
{
    const int m = blockIdx.x;
    const int f = threadIdx.x;
    const int b = m >> lg, tl = m & (R - 1);
    const int tau = tbase + tl - 1;
    if (tau < 0) {                       // token t==0: gamma is zeros (uniform per block)
        gout[(size_t)m * 128 + f] = 0.f;
        return;
    }
    __shared__ float ph_s[128], am_s[128], t1_s[128], rl_s[128], cr_s[128], av_s[128];
    __shared__ float dred[2];

    const size_t tok = (size_t)b * TT + tau;
    const float a = ac[tok], p = pc[tok];
    const float rd0 = rd[tok * 2], rd1 = rd[tok * 2 + 1];

    const float amp = tanh_(fmaf(a, w_amp[f], b_amp[f]));
    const float ph  = tanh_(fmaf(p, w_ph[f],  b_ph[f]));
    const float t1  = tanh_(fmaf(rd1, w_r1[128 + f], fmaf(rd0, w_r1[f], b_r1[f])));
    ph_s[f] = ph; am_s[f] = amp; t1_s[f] = t1;
    __syncthreads();

    float bsum = b_g[f], rsum = b_r2[f];
    #pragma unroll 4
    for (int i = 0; i < 128; ++i) bsum = fmaf(ph_s[i], w_g[i * 128 + f], bsum);
    #pragma unroll 4
    for (int i = 0; i < 128; ++i) bsum = fmaf(am_s[i], w_g[(128 + i) * 128 + f], bsum);
    #pragma unroll 4
    for (int i = 0; i < 128; ++i) rsum = fmaf(t1_s[i], w_r2[i * 128 + f], rsum);
    const float beta = sigm(bsum);
    const float corr = fmaf(beta, ph - amp, amp);
    const float rl = tanh_(rsum);
    __syncthreads();
    cr_s[f] = corr; rl_s[f] = rl;
    __syncthreads();

    float q = b_q[f], kk = b_k[f], vv = b_v[f];
    #pragma unroll 4
    for (int i = 0; i < 128; ++i) {
        q  = fmaf(cr_s[i], w_q[i * 128 + f], q);
        kk = fmaf(rl_s[i], w_k[i * 128 + f], kk);
        vv = fmaf(rl_s[i], w_v[i * 128 + f], vv);
    }
    float pd = q * kk;
    #pragma unroll
    for (int sh = 32; sh > 0; sh >>= 1) pd += __shfl_xor(pd, sh, 64);
    if ((f & 63) == 0) dred[f >> 6] = pd;
    __syncthreads();
    const float attn = sigm((dred[0] + dred[1]) * 0.088388347648318447f);
    av_s[f] = attn * vv;
    __syncthreads();

    float o = b_o[f];
    #pragma unroll 4
    for (int i = 0; i < 128; ++i) o = fmaf(av_s[i], w_o[i * 128 + f], o);
    gout[(size_t)m * 128 + f] = o;
}

// ---------- f32 pre-activation GEMM ----------
// C[m][n] = sum_k X[m][k]*Wx[k][n] + sum_i g[m][i]*sgn(gate(n))*GW[gate(n)][i][n&127]
// Block: 16 rows x 512 cols, 256 threads (thread t owns cols t and t+256).
template<int L0>
__global__ __launch_bounds__(256) void k_pre(
    const float* __restrict__ X,     // L0: hrrp [B][T][200]; else xh [MR][128]
    const float* __restrict__ gam,   // [MR][128]
    const float* __restrict__ Wx,    // x-part rows base: [Kx][512] row-major
    const float* __restrict__ GW,    // [4][128][128]
    float* __restrict__ C, int R, int lg, int tbase)
{
    const int t = threadIdx.x;
    const int m0 = blockIdx.x * 16;
    const int c0 = t, c1 = t + 256;
    __shared__ float As[16][32];
    float acc0[16], acc1[16];
    #pragma unroll
    for (int r = 0; r < 16; ++r) { acc0[r] = 0.f; acc1[r] = 0.f; }

    const int KX = L0 ? 224 : 128;   // L0 padded to 224 (zeros beyond 200)
    for (int kb = 0; kb < KX; kb += 32) {
        for (int idx = t; idx < 512; idx += 256) {
            const int r = idx >> 5, kkk = idx & 31;
            const int k = kb + kkk;
            const int m = m0 + r;
            float v = 0.f;
            if (L0) {
                if (k < 200) {
                    const int bb = m >> lg, tl = m & (R - 1);
                    v = fabsf(X[((size_t)bb * TT + tbase + tl) * DD + k]);
                }
            } else {
                v = X[(size_t)m * 128 + k];
            }
            As[r][kkk] = v;
        }
        __syncthreads();
        #pragma unroll 4
        for (int kkk = 0; kkk < 32; ++kkk) {
            const int k = kb + kkk;
            const bool valid = (!L0) || (k < 200);
            const float wv0 = valid ? Wx[(size_t)k * 512 + c0] : 0.f;
            const float wv1 = valid ? Wx[(size_t)k * 512 + c1] : 0.f;
            #pragma unroll
            for (int r = 0; r < 16; ++r) {
                const float av = As[r][kkk];
                acc0[r] = fmaf(av, wv0, acc0[r]);
                acc1[r] = fmaf(av, wv1, acc1[r]);
            }
        }
        __syncthreads();
    }

    // gamma-modulation part (sign-folded: +1, -0.5, +1, +1 per gate; LAM=0.5)
    const int gate0 = c0 >> 7, gate1 = c1 >> 7;
    const int oo0 = c0 & 127, oo1 = c1 & 127;
    const float sg0 = (gate0 == 1) ? -0.5f : 1.0f;
    const float sg1 = (gate1 == 1) ? -0.5f : 1.0f;
    for (int kb = 0; kb < 128; kb += 32) {
        for (int idx = t; idx < 512; idx += 256) {
            const int r = idx >> 5, kkk = idx & 31;
            As[r][kkk] = gam[(size_t)(m0 + r) * 128 + kb + kkk];
        }
        __syncthreads();
        #pragma unroll 4
        for (int kkk = 0; kkk < 32; ++kkk) {
            const int k = kb + kkk;
            const float wv0 = sg0 * GW[(size_t)(gate0 * 128 + k) * 128 + oo0];
            const float wv1 = sg1 * GW[(size_t)(gate1 * 128 + k) * 128 + oo1];
            #pragma unroll
            for (int r = 0; r < 16; ++r) {
                const float av = As[r][kkk];
                acc0[r] = fmaf(av, wv0, acc0[r]);
                acc1[r] = fmaf(av, wv1, acc1[r]);
            }
        }
        __syncthreads();
    }
    #pragma unroll
    for (int r = 0; r < 16; ++r) {
        C[(size_t)(m0 + r) * 512 + c0] = acc0[r];
        C[(size_t)(m0 + r) * 512 + c1] = acc1[r];
    }
}

// ---------- recurrent scan over one segment; f32 weights in registers ----------
template<int STORE_XH, int FINAL>
__global__ __launch_bounds__(512, 2) void k_scan(
    const float* __restrict__ pre, const float* __restrict__ Wh,
    const float* __restrict__ bp,
    float* __restrict__ st_h, float* __restrict__ st_c,
    float* __restrict__ xh, float* __restrict__ outp,
    const float* __restrict__ regw, const float* __restrict__ regb,
    int first, int R)
{
    const int o = threadIdx.x;
    const int b = blockIdx.x;
    __shared__ alignas(16) float hbuf[128];
    __shared__ float zbuf[512];
    float wc[128];
    #pragma unroll
    for (int i = 0; i < 128; ++i) wc[i] = Wh[i * 512 + o];
    const float bias = bp[o];
    float c = 0.f;
    if (o < 128) {
        float h0 = 0.f;
        if (!first) { h0 = st_h[b * 128 + o]; c = st_c[b * 128 + o]; }
        hbuf[o] = h0;
    }
    __syncthreads();
    const float* preb = pre + (size_t)b * R * 512;
    float p = preb[o];
    for (int t = 0; t < R; ++t) {
        const float q = (t < R - 1) ? preb[(t + 1) * 512 + o] : 0.f;
        float acc_a = p + bias, acc_b = 0.f;
        #pragma unroll
        for (int i8 = 0; i8 < 16; ++i8) {
            const float4 ha = *(const float4*)&hbuf[i8 * 8];
            const float4 hb = *(const float4*)&hbuf[i8 * 8 + 4];
            acc_a = fmaf(ha.x, wc[i8 * 8 + 0], acc_a);
            acc_b = fmaf(hb.x, wc[i8 * 8 + 4], acc_b);
            acc_a = fmaf(ha.y, wc[i8 * 8 + 1], acc_a);
            acc_b = fmaf(hb.y, wc[i8 * 8 + 5], acc_b);
            acc_a = fmaf(ha.z, wc[i8 * 8 + 2], acc_a);
            acc_b = fmaf(hb.z, wc[i8 * 8 + 6], acc_b);
            acc_a = fmaf(ha.w, wc[i8 * 8 + 3], acc_a);
            acc_b = fmaf(hb.w, wc[i8 * 8 + 7], acc_b);
        }
        zbuf[o] = acc_a + acc_b;
        __syncthreads();
        if (o < 128) {
            const float ig = sigm(zbuf[o]);
            const float fg = sigm(zbuf[o + 128]);
            const float ch = tanh_(zbuf[o + 256]);
            const float og = sigm(zbuf[o + 384]);
            c = fg * c + ig * ch;
            const float h2 = og * tanh_(c);
            hbuf[o] = h2;
            if (STORE_XH) xh[((size_t)b * R + t) * 128 + o] = h2;
        }
        __syncthreads();
        p = q;
    }
    if (o < 128) { st_h[b * 128 + o] = hbuf[o]; st_c[b * 128 + o] = c; }
    if (FINAL && o < 2) {
        float s = regb[o];
        #pragma unroll 4
        for (int i = 0; i < 128; ++i) s = fmaf(hbuf[i], regw[i * 2 + o], s);
        outp[b * 2 + o] = s;   // f32 output — reference returns float32
    }
}

// ---------- host ----------
extern "C" void kernel_launch(void* const* d_in, const int* in_sizes, int n_in,
                              void* d_out, int out_size, void* d_ws, size_t ws_size,
                              hipStream_t stream)
{
    const float* hrrp = (const float*)d_in[0];
    const float* ac   = (const float*)d_in[1];
    const float* pc   = (const float*)d_in[2];
    const float* rd   = (const float*)d_in[3];
    const float* w_amp= (const float*)d_in[4];
    const float* b_amp= (const float*)d_in[5];
    const float* w_ph = (const float*)d_in[6];
    const float* b_ph = (const float*)d_in[7];
    const float* w_g  = (const float*)d_in[8];
    const float* b_g  = (const float*)d_in[9];
    const float* w_r1 = (const float*)d_in[10];
    const float* b_r1 = (const float*)d_in[11];
    const float* w_r2 = (const float*)d_in[12];
    const float* b_r2 = (const float*)d_in[13];
    const float* w_q  = (const float*)d_in[14];
    const float* b_q  = (const float*)d_in[15];
    const float* w_k  = (const float*)d_in[16];
    const float* b_k  = (const float*)d_in[17];
    const float* w_v  = (const float*)d_in[18];
    const float* b_v  = (const float*)d_in[19];
    const float* w_o  = (const float*)d_in[20];
    const float* b_o  = (const float*)d_in[21];
    const float* w0   = (const float*)d_in[22];
    const float* b0   = (const float*)d_in[23];
    const float* gw0  = (const float*)d_in[24];
    const float* w12  = (const float*)d_in[25];
    const float* b12  = (const float*)d_in[26];
    const float* gw12 = (const float*)d_in[27];
    const float* regw = (const float*)d_in[28];
    const float* regb = (const float*)d_in[29];
    float* outp = (float*)d_out;

    // runtime segment length by workspace (constant across calls)
    int R, lg;
    if (ws_size >= 51118080ULL)      { R = 64; lg = 6; }
    else if (ws_size >= 25952256ULL) { R = 32; lg = 5; }
    else return;
    const int NSEG = TT / R;
    const int MR = BB * R;

    char* ws = (char*)d_ws;
    size_t off = 0;
    float* pre  = (float*)(ws + off); off += (size_t)MR * 512 * 4;
    float* gamf = (float*)(ws + off); off += (size_t)MR * 128 * 4;
    float* xh   = (float*)(ws + off); off += (size_t)MR * 128 * 4;
    float* sh0 = (float*)(ws + off); off += 131072;
    float* sc0 = (float*)(ws + off); off += 131072;
    float* sh1 = (float*)(ws + off); off += 131072;
    float* sc1 = (float*)(ws + off); off += 131072;
    float* sh2 = (float*)(ws + off); off += 131072;
    float* sc2 = (float*)(ws + off); off += 131072;

    const float* w0x  = w0 + 128 * 512;           // x-part rows of layer-0 W
    const float* w1x  = w12 + (0 * 256 + 128) * 512;
    const float* w2x  = w12 + (1 * 256 + 128) * 512;
    const float* gw1  = gw12;
    const float* gw2  = gw12 + 4 * 128 * 128;

    for (int seg = 0; seg < NSEG; ++seg) {
        const int first = (seg == 0) ? 1 : 0;
        const int tbase = seg * R;
        k_gamma<<<MR, 128, 0, stream>>>(ac, pc, rd, w_amp, b_amp, w_ph, b_ph,
                                        w_g, b_g, w_r1, b_r1, w_r2, b_r2,
                                        w_q, b_q, w_k, b_k, w_v, b_v, w_o, b_o,
                                        gamf, R, lg, tbase);
        // layer 0
        k_pre<1><<<MR / 16, 256, 0, stream>>>(hrrp, gamf, w0x, gw0, pre, R, lg, tbase);
        k_scan<1, 0><<<BB, 512, 0, stream>>>(pre, w0, b0, sh0, sc0, xh,
                                             nullptr, nullptr, nullptr, first, R);
        // layer 1
        k_pre<0><<<MR / 16, 256, 0, stream>>>(xh, gamf, w1x, gw1, pre, R, lg, tbase);
        k_scan<1, 0><<<BB, 512, 0, stream>>>(pre, w12, b12, sh1, sc1, xh,
                                             nullptr, nullptr, nullptr, first, R);
        // layer 2
        k_pre<0><<<MR / 16, 256, 0, stream>>>(xh, gamf, w2x, gw2, pre, R, lg, tbase);
        if (seg < NSEG - 1)
            k_scan<0, 0><<<BB, 512, 0, stream>>>(pre, w12 + 256 * 512, b12 + 512, sh2, sc2,
                                                 nullptr, nullptr, nullptr, nullptr, first, R);
        else
            k_scan<0, 1><<<BB, 512, 0, stream>>>(pre, w12 + 256 * 512, b12 + 512, sh2, sc2,
                                                 nullptr, outp, regw, regb, first, R);
    }
}

// Round 6
// 4278.469 us; speedup vs baseline: 1.8425x; 1.8425x over previous
//
#include <hip/hip_runtime.h>

#define BB 256
#define TT 512
#define DD 200

// ---------- helpers ----------
__device__ __forceinline__ float bf2f(unsigned short u) {
    return __uint_as_float(((unsigned int)u) << 16);
}
__device__ __forceinline__ unsigned short f2bf(float f) {
    unsigned int u = __float_as_uint(f);
    u += 0x7FFFu + ((u >> 16) & 1u);
    return (unsigned short)(u >> 16);
}
__device__ __forceinline__ float sigm(float x) { return 1.0f / (1.0f + __expf(-x)); }
__device__ __forceinline__ float tanh_(float x) { return 1.0f - 2.0f / (__expf(2.0f * x) + 1.0f); }

typedef __bf16 bf16x8 __attribute__((ext_vector_type(8)));
typedef float  f32x4  __attribute__((ext_vector_type(4)));

#define GPAD 20

#define MAC16(ACCV, BASE, W) do { \
    const float4* _p4 = (const float4*)(BASE); \
    float4 _v0 = _p4[0], _v1 = _p4[1], _v2 = _p4[2], _v3 = _p4[3]; \
    ACCV[0]  = fmaf(_v0.x,(W),ACCV[0]);  ACCV[1]  = fmaf(_v0.y,(W),ACCV[1]); \
    ACCV[2]  = fmaf(_v0.z,(W),ACCV[2]);  ACCV[3]  = fmaf(_v0.w,(W),ACCV[3]); \
    ACCV[4]  = fmaf(_v1.x,(W),ACCV[4]);  ACCV[5]  = fmaf(_v1.y,(W),ACCV[5]); \
    ACCV[6]  = fmaf(_v1.z,(W),ACCV[6]);  ACCV[7]  = fmaf(_v1.w,(W),ACCV[7]); \
    ACCV[8]  = fmaf(_v2.x,(W),ACCV[8]);  ACCV[9]  = fmaf(_v2.y,(W),ACCV[9]); \
    ACCV[10] = fmaf(_v2.z,(W),ACCV[10]); ACCV[11] = fmaf(_v2.w,(W),ACCV[11]); \
    ACCV[12] = fmaf(_v3.x,(W),ACCV[12]); ACCV[13] = fmaf(_v3.y,(W),ACCV[13]); \
    ACCV[14] = fmaf(_v3.z,(W),ACCV[14]); ACCV[15] = fmaf(_v3.w,(W),ACCV[15]); \
} while (0)

// ---------- build B matrices (bf16 hi/lo 3-term layout) from f32 weights ----------
// b0t [512][1056]: k<672: blk=k/224 (0:Whi,1:Wlo,2:Whi) of W0 x-rows (col<200, else 0)
//                  k>=672: kg=k-672, blkg=kg>>7 (0:GWhi,1:GWlo,2:GWhi), sgn-folded
// b1t/b2t [512][768]: k<384: blk=k>>7 over Wx rows 128..255; k>=384: GW blocks
__global__ __launch_bounds__(256) void k_prep_b(
    const float* __restrict__ w0, const float* __restrict__ gw0,
    const float* __restrict__ w12, const float* __restrict__ gw12,
    unsigned short* __restrict__ b0t, unsigned short* __restrict__ b1t,
    unsigned short* __restrict__ b2t)
{
    const int n = blockIdx.x;
    const int gate = n >> 7, oo = n & 127;
    const float sgn = (gate == 1) ? -0.5f : 1.0f;
    for (int k = threadIdx.x; k < 1056; k += 256) {
        float w; int isLo;
        if (k < 672) {
            int blk = k / 224, col = k - blk * 224;
            w = (col < 200) ? w0[(size_t)(128 + col) * 512 + n] : 0.f;
            isLo = (blk == 1);
        } else {
            int kg = k - 672, blkg = kg >> 7, colg = kg & 127;
            w = sgn * gw0[(size_t)(gate * 128 + colg) * 128 + oo];
            isLo = (blkg == 1);
        }
        unsigned short hi = f2bf(w);
        b0t[(size_t)n * 1056 + k] = isLo ? f2bf(w - bf2f(hi)) : hi;
    }
    for (int l = 0; l < 2; ++l) {
        unsigned short* dst = l ? b2t : b1t;
        for (int k = threadIdx.x; k < 768; k += 256) {
            float w; int isLo;
            if (k < 384) {
                int blk = k >> 7, col = k & 127;
                w = w12[(size_t)(l * 256 + 128 + col) * 512 + n];
                isLo = (blk == 1);
            } else {
                int kg = k - 384, blkg = kg >> 7, colg = kg & 127;
                w = sgn * gw12[(size_t)((l * 4 + gate) * 128 + colg) * 128 + oo];
                isLo = (blkg == 1);
            }
            unsigned short hi = f2bf(w);
            dst[(size_t)n * 768 + k] = isLo ? f2bf(w - bf2f(hi)) : hi;
        }
    }
}

// ---------- TwoStageFusion -> gsh (pre-shifted gamma, bf16 hi/lo), 16 tokens/block ----------
__global__ __launch_bounds__(128) void k_gamma(
    const float* __restrict__ ac, const float* __restrict__ pc,
    const float* __restrict__ rd,
    const float* __restrict__ w_amp, const float* __restrict__ b_amp,
    const float* __restrict__ w_ph,  const float* __restrict__ b_ph,
    const float* __restrict__ w_g,   const float* __restrict__ b_g,
    const float* __restrict__ w_r1,  const float* __restrict__ b_r1,
    const float* __restrict__ w_r2,  const float* __restrict__ b_r2,
    const float* __restrict__ w_q,   const float* __restrict__ b_q,
    const float* __restrict__ w_k,   const float* __restrict__ b_k,
    const float* __restrict__ w_v,   const float* __restrict__ b_v,
    const float* __restrict__ w_o,   const float* __restrict__ b_o,
    unsigned short* __restrict__ gsh, int segLen, int lgSeg, int tbase)
{
    __shared__ alignas(16) float catT[256][GPAD];
    __shared__ alignas(16) float rlT[128][GPAD];
    __shared__ alignas(16) float avT[128][GPAD];
    __shared__ float scin[4][16];
    __shared__ float red[2][16];

    const int f = threadIdx.x;
    const int r0 = blockIdx.x * 16;
    const int b = r0 >> lgSeg;
    const int tl = r0 & (segLen - 1);
    const int tau0 = tbase + tl - 1;

    if (f < 64) {
        int j = f >> 4, tt = f & 15;
        int tau = tau0 + tt; if (tau < 0) tau = 0;
        size_t tok = (size_t)b * TT + tau;
        float v;
        if (j == 0) v = ac[tok];
        else if (j == 1) v = pc[tok];
        else v = rd[tok * 2 + (j - 2)];
        scin[j][tt] = v;
    }
    const float wa = w_amp[f], ba = b_amp[f];
    const float wp = w_ph[f],  bpv = b_ph[f];
    const float w1a = w_r1[f], w1b = w_r1[128 + f];
    const float br1 = b_r1[f], br2 = b_r2[f];
    const float bg = b_g[f];
    const float bqv = b_q[f], bkv = b_k[f];
    const float bvv = b_v[f], bov = b_o[f];
    __syncthreads();

    float ph16[16], am16[16];
    #pragma unroll
    for (int t = 0; t < 16; ++t) {
        float a = scin[0][t], p = scin[1][t], r0v = scin[2][t], r1v = scin[3][t];
        float phv = tanh_(fmaf(p, wp, bpv));
        float amv = tanh_(fmaf(a, wa, ba));
        ph16[t] = phv; am16[t] = amv;
        catT[f][t] = phv;
        catT[128 + f][t] = amv;
        rlT[f][t] = tanh_(fmaf(r1v, w1b, fmaf(r0v, w1a, br1)));
    }
    __syncthreads();

    float bacc[16], racc[16];
    #pragma unroll
    for (int t = 0; t < 16; ++t) { bacc[t] = 0.f; racc[t] = 0.f; }
    #pragma unroll 2
    for (int i = 0; i < 128; ++i) {
        float wg1 = w_g[i * 128 + f];
        float wg2 = w_g[(128 + i) * 128 + f];
        float wr  = w_r2[i * 128 + f];
        MAC16(bacc, &catT[i][0], wg1);
        MAC16(bacc, &catT[128 + i][0], wg2);
        MAC16(racc, &rlT[i][0], wr);
    }
    float corr16[16], rl16[16];
    #pragma unroll
    for (int t = 0; t < 16; ++t) {
        float beta = sigm(bacc[t] + bg);
        corr16[t] = fmaf(beta, ph16[t] - am16[t], am16[t]);
        rl16[t] = tanh_(racc[t] + br2);
    }
    __syncthreads();
    #pragma unroll
    for (int t = 0; t < 16; ++t) { catT[f][t] = corr16[t]; rlT[f][t] = rl16[t]; }
    __syncthreads();

    float qa[16], ka[16], va[16];
    #pragma unroll
    for (int t = 0; t < 16; ++t) { qa[t] = 0.f; ka[t] = 0.f; va[t] = 0.f; }
    #pragma unroll 2
    for (int i = 0; i < 128; ++i) {
        float wq = w_q[i * 128 + f];
        float wk = w_k[i * 128 + f];
        float wv = w_v[i * 128 + f];
        MAC16(qa, &catT[i][0], wq);
        MAC16(ka, &rlT[i][0], wk);
        MAC16(va, &rlT[i][0], wv);
    }
    const int lane = f & 63, wvi = f >> 6;
    #pragma unroll
    for (int t = 0; t < 16; ++t) {
        float pdot = (qa[t] + bqv) * (ka[t] + bkv);
        #pragma unroll
        for (int sh = 32; sh > 0; sh >>= 1) pdot += __shfl_xor(pdot, sh, 64);
        if (lane == 0) red[wvi][t] = pdot;
    }
    __syncthreads();
    #pragma unroll
    for (int t = 0; t < 16; ++t) {
        float attn = sigm((red[0][t] + red[1][t]) * 0.088388347648318447f);
        avT[f][t] = attn * (va[t] + bvv);
    }
    __syncthreads();
    float oacc[16];
    #pragma unroll
    for (int t = 0; t < 16; ++t) oacc[t] = 0.f;
    #pragma unroll 2
    for (int i = 0; i < 128; ++i) {
        float wo = w_o[i * 128 + f];
        MAC16(oacc, &avT[i][0], wo);
    }
    #pragma unroll
    for (int t = 0; t < 16; ++t) {
        float g = oacc[t] + bov;
        if (tau0 + t < 0) g = 0.f;
        unsigned short hi = f2bf(g);
        gsh[(size_t)(r0 + t) * 256 + f] = hi;
        gsh[(size_t)(r0 + t) * 256 + 128 + f] = f2bf(g - bf2f(hi));
    }
}

// ---------- stage |hrrp| into bf16 hi/lo  xs[m][0:224]=hi, [224:448]=lo ----------
__global__ __launch_bounds__(256) void k_stagex(
    const float* __restrict__ hrrp, unsigned short* __restrict__ xs,
    int segLen, int lgSeg, int tbase)
{
    const int m = blockIdx.x;
    const int b = m >> lgSeg, tl = m & (segLen - 1);
    const size_t bt = (size_t)b * TT + tbase + tl;
    const int col = threadIdx.x;
    if (col < 224) {
        float v = (col < 200) ? fabsf(hrrp[bt * DD + col]) : 0.f;
        unsigned short hi = f2bf(v);
        xs[(size_t)m * 448 + col] = hi;
        xs[(size_t)m * 448 + 224 + col] = f2bf(v - bf2f(hi));
    }
}

// ---------- A-fragment mapping for 3-term layout ----------
template<int KTOT>
__device__ __forceinline__ uint4 loadA(const unsigned short* __restrict__ Ax,
                                       const unsigned short* __restrict__ Ag,
                                       int m, int ko)
{
    if (KTOT == 1056) {
        if (ko < 672) {
            int blk = ko / 224, col = ko - blk * 224;
            return *(const uint4*)(Ax + (size_t)m * 448 + (blk == 2 ? 224 : 0) + col);
        }
        int kg = ko - 672, blkg = kg >> 7, colg = kg & 127;
        return *(const uint4*)(Ag + (size_t)m * 256 + (blkg == 2 ? 128 : 0) + colg);
    } else {
        if (ko < 384) {
            int blk = ko >> 7, col = ko & 127;
            return *(const uint4*)(Ax + (size_t)m * 256 + (blk == 2 ? 128 : 0) + col);
        }
        int kg = ko - 384, blkg = kg >> 7, colg = kg & 127;
        return *(const uint4*)(Ag + (size_t)m * 256 + (blkg == 2 ? 128 : 0) + colg);
    }
}

// ---------- bf16 MFMA GEMM  C[M][512] = A_ext[M][KTOT] * Bt[512][KTOT]^T ----------
template<int KTOT>
__global__ __launch_bounds__(256) void k_gemm(
    const unsigned short* __restrict__ Ax, const unsigned short* __restrict__ Ag,
    const unsigned short* __restrict__ Bt, float* __restrict__ C)
{
    __shared__ alignas(16) unsigned short Als[128 * 32];
    __shared__ alignas(16) unsigned short Bls[128 * 32];
    const int tid = threadIdx.x;
    const int m0 = blockIdx.x * 128, n0 = blockIdx.y * 128;
    const int wave = tid >> 6, lane = tid & 63;
    const int lm = lane & 15, lq = lane >> 4;
    const int wm = wave >> 1, wn = wave & 1;
    const int srow = tid >> 2, scol = (tid & 3) * 8;

    const f32x4 vzero = {0.f, 0.f, 0.f, 0.f};
    f32x4 acc[4][4];
    #pragma unroll
    for (int x = 0; x < 4; ++x)
        #pragma unroll
        for (int y = 0; y < 4; ++y) acc[x][y] = vzero;

    for (int kb = 0; kb < KTOT / 32; ++kb) {
        const int ko = kb * 32 + scol;
        uint4 a0 = loadA<KTOT>(Ax, Ag, m0 + srow, ko);
        uint4 a1 = loadA<KTOT>(Ax, Ag, m0 + 64 + srow, ko);
        uint4 c0 = *(const uint4*)(Bt + (size_t)(n0 + srow) * KTOT + ko);
        uint4 c1 = *(const uint4*)(Bt + (size_t)(n0 + 64 + srow) * KTOT + ko);
        if (kb) __syncthreads();
        *(uint4*)&Als[srow * 32 + scol] = a0;
        *(uint4*)&Als[(64 + srow) * 32 + scol] = a1;
        *(uint4*)&Bls[srow * 32 + scol] = c0;
        *(uint4*)&Bls[(64 + srow) * 32 + scol] = c1;
        __syncthreads();
        bf16x8 af[4], bfr[4];
        #pragma unroll
        for (int mt = 0; mt < 4; ++mt)
            af[mt] = *(const bf16x8*)&Als[(wm * 64 + mt * 16 + lm) * 32 + lq * 8];
        #pragma unroll
        for (int nt = 0; nt < 4; ++nt)
            bfr[nt] = *(const bf16x8*)&Bls[(wn * 64 + nt * 16 + lm) * 32 + lq * 8];
        #pragma unroll
        for (int mt = 0; mt < 4; ++mt)
            #pragma unroll
            for (int nt = 0; nt < 4; ++nt)
                acc[mt][nt] = __builtin_amdgcn_mfma_f32_16x16x32_bf16(af[mt], bfr[nt], acc[mt][nt], 0, 0, 0);
    }
    #pragma unroll
    for (int mt = 0; mt < 4; ++mt) {
        #pragma unroll
        for (int nt = 0; nt < 4; ++nt) {
            const int m = m0 + wm * 64 + mt * 16 + lq * 4;
            const int n = n0 + wn * 64 + nt * 16 + lm;
            #pragma unroll
            for (int r = 0; r < 4; ++r)
                C[(size_t)(m + r) * 512 + n] = acc[mt][nt][r];
        }
    }
}

// ---------- recurrent scan over one segment; f32 weights in registers ----------
template<int STORE_XH, int FINAL>
__global__ __launch_bounds__(512, 2) void k_scan(
    const float* __restrict__ pre, const float* __restrict__ Wh,
    const float* __restrict__ bp,
    float* __restrict__ st_h, float* __restrict__ st_c,
    unsigned short* __restrict__ xh, float* __restrict__ outp,
    const float* __restrict__ regw, const float* __restrict__ regb,
    int first, int R)
{
    const int o = threadIdx.x;
    const int b = blockIdx.x;
    __shared__ alignas(16) float hbuf[128];
    __shared__ float zbuf[512];
    float wc[128];
    #pragma unroll
    for (int i = 0; i < 128; ++i) wc[i] = Wh[i * 512 + o];
    const float bias = bp[o];
    float c = 0.f;
    if (o < 128) {
        float h0 = 0.f;
        if (!first) { h0 = st_h[b * 128 + o]; c = st_c[b * 128 + o]; }
        hbuf[o] = h0;
    }
    __syncthreads();
    const float* preb = pre + (size_t)b * R * 512;
    float p = preb[o];
    for (int t = 0; t < R; ++t) {
        const float q = (t < R - 1) ? preb[(t + 1) * 512 + o] : 0.f;
        float acc_a = p + bias, acc_b = 0.f;
        #pragma unroll
        for (int i8 = 0; i8 < 16; ++i8) {
            const float4 ha = *(const float4*)&hbuf[i8 * 8];
            const float4 hb = *(const float4*)&hbuf[i8 * 8 + 4];
            acc_a = fmaf(ha.x, wc[i8 * 8 + 0], acc_a);
            acc_b = fmaf(hb.x, wc[i8 * 8 + 4], acc_b);
            acc_a = fmaf(ha.y, wc[i8 * 8 + 1], acc_a);
            acc_b = fmaf(hb.y, wc[i8 * 8 + 5], acc_b);
            acc_a = fmaf(ha.z, wc[i8 * 8 + 2], acc_a);
            acc_b = fmaf(hb.z, wc[i8 * 8 + 6], acc_b);
            acc_a = fmaf(ha.w, wc[i8 * 8 + 3], acc_a);
            acc_b = fmaf(hb.w, wc[i8 * 8 + 7], acc_b);
        }
        zbuf[o] = acc_a + acc_b;
        __syncthreads();
        if (o < 128) {
            const float ig = sigm(zbuf[o]);
            const float fg = sigm(zbuf[o + 128]);
            const float ch = tanh_(zbuf[o + 256]);
            const float og = sigm(zbuf[o + 384]);
            c = fg * c + ig * ch;
            const float h2 = og * tanh_(c);
            hbuf[o] = h2;
            if (STORE_XH) {
                unsigned short hi = f2bf(h2);
                size_t row = (size_t)b * R + t;
                xh[row * 256 + o] = hi;
                xh[row * 256 + 128 + o] = f2bf(h2 - bf2f(hi));
            }
        }
        __syncthreads();
        p = q;
    }
    if (o < 128) { st_h[b * 128 + o] = hbuf[o]; st_c[b * 128 + o] = c; }
    if (FINAL && o < 2) {
        float s = regb[o];
        #pragma unroll 4
        for (int i = 0; i < 128; ++i) s = fmaf(hbuf[i], regw[i * 2 + o], s);
        outp[b * 2 + o] = s;   // f32 output
    }
}

// ---------- host ----------
extern "C" void kernel_launch(void* const* d_in, const int* in_sizes, int n_in,
                              void* d_out, int out_size, void* d_ws, size_t ws_size,
                              hipStream_t stream)
{
    const float* hrrp = (const float*)d_in[0];
    const float* ac   = (const float*)d_in[1];
    const float* pc   = (const float*)d_in[2];
    const float* rd   = (const float*)d_in[3];
    const float* w_amp= (const float*)d_in[4];
    const float* b_amp= (const float*)d_in[5];
    const float* w_ph = (const float*)d_in[6];
    const float* b_ph = (const float*)d_in[7];
    const float* w_g  = (const float*)d_in[8];
    const float* b_g  = (const float*)d_in[9];
    const float* w_r1 = (const float*)d_in[10];
    const float* b_r1 = (const float*)d_in[11];
    const float* w_r2 = (const float*)d_in[12];
    const float* b_r2 = (const float*)d_in[13];
    const float* w_q  = (const float*)d_in[14];
    const float* b_q  = (const float*)d_in[15];
    const float* w_k  = (const float*)d_in[16];
    const float* b_k  = (const float*)d_in[17];
    const float* w_v  = (const float*)d_in[18];
    const float* b_v  = (const float*)d_in[19];
    const float* w_o  = (const float*)d_in[20];
    const float* b_o  = (const float*)d_in[21];
    const float* w0   = (const float*)d_in[22];
    const float* b0   = (const float*)d_in[23];
    const float* gw0  = (const float*)d_in[24];
    const float* w12  = (const float*)d_in[25];
    const float* b12  = (const float*)d_in[26];
    const float* gw12 = (const float*)d_in[27];
    const float* regw = (const float*)d_in[28];
    const float* regb = (const float*)d_in[29];
    float* outp = (float*)d_out;

    // segment length chosen by available workspace (constant across calls)
    const size_t need64 = 68452352ULL, need32 = 35946496ULL;
    int R, lg;
    if (ws_size >= need64) { R = 64; lg = 6; }
    else if (ws_size >= need32) { R = 32; lg = 5; }
    else return;
    const int NSEG = TT / R;
    const int MR = BB * R;

    char* ws = (char*)d_ws;
    size_t off = 0;
    float* pre = (float*)(ws + off);                   off += (size_t)MR * 512 * 4;
    unsigned short* gsh = (unsigned short*)(ws + off); off += (size_t)MR * 256 * 2;
    unsigned short* xh  = (unsigned short*)(ws + off); off += (size_t)MR * 256 * 2;
    unsigned short* xs  = (unsigned short*)(ws + off); off += (size_t)MR * 448 * 2;
    float* sh0 = (float*)(ws + off); off += 131072;
    float* sc0 = (float*)(ws + off); off += 131072;
    float* sh1 = (float*)(ws + off); off += 131072;
    float* sc1 = (float*)(ws + off); off += 131072;
    float* sh2 = (float*)(ws + off); off += 131072;
    float* sc2 = (float*)(ws + off); off += 131072;
    unsigned short* b0t = (unsigned short*)(ws + off); off += 512 * 1056 * 2;
    unsigned short* b1t = (unsigned short*)(ws + off); off += 512 * 768 * 2;
    unsigned short* b2t = (unsigned short*)(ws + off); off += 512 * 768 * 2;

    k_prep_b<<<512, 256, 0, stream>>>(w0, gw0, w12, gw12, b0t, b1t, b2t);

    for (int seg = 0; seg < NSEG; ++seg) {
        const int first = (seg == 0) ? 1 : 0;
        const int tbase = seg * R;
        k_gamma<<<MR / 16, 128, 0, stream>>>(ac, pc, rd, w_amp, b_amp, w_ph, b_ph,
                                             w_g, b_g, w_r1, b_r1, w_r2, b_r2,
                                             w_q, b_q, w_k, b_k, w_v, b_v, w_o, b_o,
                                             gsh, R, lg, tbase);
        k_stagex<<<MR, 256, 0, stream>>>(hrrp, xs, R, lg, tbase);
        // layer 0
        k_gemm<1056><<<dim3(MR / 128, 4), 256, 0, stream>>>(xs, gsh, b0t, pre);
        k_scan<1, 0><<<BB, 512, 0, stream>>>(pre, w0, b0, sh0, sc0, xh,
                                             nullptr, nullptr, nullptr, first, R);
        // layer 1
        k_gemm<768><<<dim3(MR / 128, 4), 256, 0, stream>>>(xh, gsh, b1t, pre);
        k_scan<1, 0><<<BB, 512, 0, stream>>>(pre, w12, b12, sh1, sc1, xh,
                                             nullptr, nullptr, nullptr, first, R);
        // layer 2
        k_gemm<768><<<dim3(MR / 128, 4), 256, 0, stream>>>(xh, gsh, b2t, pre);
        if (seg < NSEG - 1)
            k_scan<0, 0><<<BB, 512, 0, stream>>>(pre, w12 + 256 * 512, b12 + 512, sh2, sc2,
                                                 nullptr, nullptr, nullptr, nullptr, first, R);
        else
            k_scan<0, 1><<<BB, 512, 0, stream>>>(pre, w12 + 256 * 512, b12 + 512, sh2, sc2,
                                                 nullptr, outp, regw, regb, first, R);
    }
}